// Round 6
// baseline (434.631 us; speedup 1.0000x reference)
//
#include <hip/hip_runtime.h>

#define TT 512
#define BB 256
#define DD 128
#define HH 128
#define QQ 8
#define INV2PI 0.15915494309189535f

struct Params {
    const float* x;
    const float* W[4];
    const float* b[4];
    const float* th[4];
    const float* U[4];
    const float* cb[4];
    float* out;
};

__device__ __forceinline__ float rcp_f(float x)  { return __builtin_amdgcn_rcpf(x); }
__device__ __forceinline__ float exp2_f(float x) { return __builtin_amdgcn_exp2f(x); }

// DPP move for sum-butterflies (old=0, bound_ctrl=on)
template<int CTRL>
__device__ __forceinline__ float dpp_mov(float x) {
    int r = __builtin_amdgcn_update_dpp(0, __float_as_int(x), CTRL, 0xF, 0xF, true);
    return __int_as_float(r);
}
// DPP with multiplicative-identity fallback: masked/invalid lanes receive 1.0f.
template<int CTRL, int RM>
__device__ __forceinline__ float dpp_mul1(float x) {
    int r = __builtin_amdgcn_update_dpp(0x3f800000 /*1.0f*/, __float_as_int(x),
                                        CTRL, RM, 0xF, false);
    return __int_as_float(r);
}
#define RDLANE(v, l) __int_as_float(__builtin_amdgcn_readlane(__float_as_int(v), (l)))

// Barrier without vmcnt drain (LDS ordering only) — global loads stay in flight.
__device__ __forceinline__ void bar_lds() {
    asm volatile("s_waitcnt lgkmcnt(0)\n\ts_barrier" ::: "memory");
}

// One block per batch element; 8 waves, ONE launch (R3 lesson: each extra
// launch costs ~110us fixed overhead).
//   waves 0-3: R3's recurrence verbatim (measured-best, 1076 cy/step):
//     phase A (zh dot + qgate + Uexp) | bar | phase B (waves 0-1: E) | bar.
//     zx is read directly from the LDS ring zxr[t] (bias+theta pre-folded,
//     everything pre-scaled by 1/2pi so cos = v_fract+v_cos).
//   waves 4-7: zx producers. Prologue fills t<64 (pipelined global loads);
//     then ONE t per consumer step inside the same loop, executing the same
//     two barriers (uniform barrier count -> no deadlock). Race-free by
//     construction: consumer step t reads slot t, producers write slots
//     64+4t+{0..3} > t, each slot written once, no wrap. Producers are done
//     by step ~112, thereafter they just hit barriers. Producer step work
//     ~160cy << consumer ~450cy; loads prefetched one step (~1000cy) ahead.
// R4 lesson (single-wave consumer = 1477 cy/step latency-bound) and R1
// lesson (E-dup + single barrier = +470cy) both rejected; 4-wave split stays.
// LDS pad for hbuf: slot(k) = k + 4*(k>>5).
__global__ __launch_bounds__(512, 1) void qlstm(Params p) {
    __shared__ __align__(16) float zxr[TT][32];   // 64KB: zx(+b+th), /2pi
    __shared__ __align__(16) float hbuf[144];     // h_{t-1}, padded
    __shared__ float pre[512];                    // gate preacts (scaled)

    const int tid = threadIdx.x;
    const int bId = blockIdx.x;
    const int ln  = tid & 63;
    const int wv  = tid >> 6;        // 0-3 consumer (== gate), 4-7 producer
    const int qub = ln >> 3;
    const int part8 = ln & 7;

    // ---- consumer state ----
    float Wh[16];
    float Ua[8], Ub[8], cba = 0.f, cbb = 0.f;
    // ---- producer state ----
    float4 wx[16], xr[16];
    float bb = 0.f;
    int tp = 0, pgq = 0, phalf = 0;
    const float* xb = nullptr;

    if (wv < 4) {
        const float* Wg = p.W[wv] + qub * (DD + HH) + DD + part8 * 16;
        #pragma unroll
        for (int j = 0; j < 16; ++j) Wh[j] = Wg[j] * INV2PI;
        const float esc = (wv == 2) ? 2.885390081777927f : -1.442695040888963f;
        #pragma unroll
        for (int j = 0; j < 8; ++j) {
            Ua[j] = p.U[wv][ln * QQ + j] * esc;
            Ub[j] = p.U[wv][(ln + 64) * QQ + j] * esc;
        }
        cba = p.cb[wv][ln] * esc;
        cbb = p.cb[wv][ln + 64] * esc;
        if (tid < 128) hbuf[tid + 4 * (tid >> 5)] = 0.f;
    } else {
        pgq   = ln >> 1;             // 0..31: gate = pgq>>3, qubit = pgq&7
        phalf = ln & 1;              // x-half
        const float* Wp = p.W[pgq >> 3] + (pgq & 7) * (DD + HH) + phalf * 64;
        #pragma unroll
        for (int j = 0; j < 16; ++j) {
            float4 w = *(const float4*)(Wp + 4 * j);
            wx[j] = make_float4(w.x * INV2PI, w.y * INV2PI,
                                w.z * INV2PI, w.w * INV2PI);
        }
        bb = (p.b[pgq >> 3][pgq & 7] + p.th[pgq >> 3][pgq & 7]) * INV2PI;
        xb = p.x + (size_t)bId * DD + phalf * 64;
        tp = wv - 4;
        {   // preload tile for tp
            const float* xp = xb + (size_t)tp * (BB * DD);
            #pragma unroll
            for (int j = 0; j < 16; ++j) xr[j] = *(const float4*)(xp + 4 * j);
        }
        // prologue: produce t < 64 (16 iters), software-pipelined loads
        for (int i = 0; i < 16; ++i) {
            float b0 = wx[0].x * xr[0].x, b1 = wx[0].y * xr[0].y;
            float b2 = wx[0].z * xr[0].z, b3 = wx[0].w * xr[0].w;
            #pragma unroll
            for (int j = 1; j < 16; ++j) {
                b0 = fmaf(wx[j].x, xr[j].x, b0); b1 = fmaf(wx[j].y, xr[j].y, b1);
                b2 = fmaf(wx[j].z, xr[j].z, b2); b3 = fmaf(wx[j].w, xr[j].w, b3);
            }
            float s = (b0 + b1) + (b2 + b3);
            s += dpp_mov<0xB1>(s);
            if (phalf == 0) zxr[tp][pgq] = s + bb;
            tp += 4;
            if (tp < TT) {
                const float* xp = xb + (size_t)tp * (BB * DD);
                #pragma unroll
                for (int j = 0; j < 16; ++j) xr[j] = *(const float4*)(xp + 4 * j);
            }
        }
    }

    bar_lds();   // zxr[0..63] + hbuf(0) visible to all 8 waves

    const float* hsrc = &hbuf[16 * part8 + 4 * (part8 >> 1)];
    const size_t ostep = (size_t)BB * HH;
    size_t orow = (size_t)bId * HH + tid;     // used by tid<128 only
    float cst = 0.f, hn_last = 0.f;

    #pragma unroll 8
    for (int t = 0; t < TT; ++t) {
        float pa, pb;
        if (wv < 4) {
            // ---- phase A: zh dot (LDS reads first), qgate, Uexp ----
            const float zxv = zxr[t][8 * wv + qub];    // octet broadcast
            const float4 h0 = *(const float4*)(hsrc);
            const float4 h1 = *(const float4*)(hsrc + 4);
            const float4 h2 = *(const float4*)(hsrc + 8);
            const float4 h3 = *(const float4*)(hsrc + 12);

            float a0 = Wh[0] * h0.x, a1 = Wh[1] * h0.y;
            float a2 = Wh[2] * h0.z, a3 = Wh[3] * h0.w;
            a0 = fmaf(Wh[4],  h1.x, a0); a1 = fmaf(Wh[5],  h1.y, a1);
            a2 = fmaf(Wh[6],  h1.z, a2); a3 = fmaf(Wh[7],  h1.w, a3);
            a0 = fmaf(Wh[8],  h2.x, a0); a1 = fmaf(Wh[9],  h2.y, a1);
            a2 = fmaf(Wh[10], h2.z, a2); a3 = fmaf(Wh[11], h2.w, a3);
            a0 = fmaf(Wh[12], h3.x, a0); a1 = fmaf(Wh[13], h3.y, a1);
            a2 = fmaf(Wh[14], h3.z, a2); a3 = fmaf(Wh[15], h3.w, a3);
            float acc = (a0 + a1) + (a2 + a3);
            acc += dpp_mov<0xB1>(acc);
            acc += dpp_mov<0x4E>(acc);
            acc += dpp_mov<0x141>(acc);
            acc += zxv;                         // bias+theta already folded

            // angle in revolutions: cos = v_fract + v_cos
            const float cv = __builtin_amdgcn_cosf(__builtin_amdgcn_fractf(acc));
            float v = cv;
            v *= dpp_mul1<0x118, 0xF>(v);       // row_shr:8
            v *= dpp_mul1<0x142, 0xA>(v);       // row_bcast15 -> rows 1,3
            v *= dpp_mul1<0x143, 0xC>(v);       // row_bcast31 -> rows 2,3
            float u = (ln < 8) ? 1.f : cv;      // scan excluding qubit 0
            u *= dpp_mul1<0x118, 0xF>(u);
            u *= dpp_mul1<0x142, 0xA>(u);
            u *= dpp_mul1<0x143, 0xC>(u);
            const float q0 = RDLANE(u, 63);
            const float q1 = RDLANE(v, 8);
            const float q2 = RDLANE(v, 16);
            const float q3 = RDLANE(v, 24);
            const float q4 = RDLANE(v, 32);
            const float q5 = RDLANE(v, 40);
            const float q6 = RDLANE(v, 48);
            const float q7 = RDLANE(v, 56);

            float a01 = fmaf(Ua[1], q1, Ua[0] * q0);
            float b01 = fmaf(Ub[1], q1, Ub[0] * q0);
            float a23 = fmaf(Ua[3], q3, Ua[2] * q2);
            float b23 = fmaf(Ub[3], q3, Ub[2] * q2);
            float a45 = fmaf(Ua[5], q5, Ua[4] * q4);
            float b45 = fmaf(Ub[5], q5, Ub[4] * q4);
            float a67 = fmaf(Ua[7], q7, Ua[6] * q6);
            float b67 = fmaf(Ub[7], q7, Ub[6] * q6);
            pa = ((a01 + a23) + (a45 + a67)) + cba;
            pb = ((b01 + b23) + (b45 + b67)) + cbb;
            pre[wv * 128 + ln]      = pa;
            pre[wv * 128 + 64 + ln] = pb;
        } else {
            // ---- producer: one t per step, loads prefetched last step ----
            if (tp < TT) {
                float b0 = wx[0].x * xr[0].x, b1 = wx[0].y * xr[0].y;
                float b2 = wx[0].z * xr[0].z, b3 = wx[0].w * xr[0].w;
                #pragma unroll
                for (int j = 1; j < 16; ++j) {
                    b0 = fmaf(wx[j].x, xr[j].x, b0);
                    b1 = fmaf(wx[j].y, xr[j].y, b1);
                    b2 = fmaf(wx[j].z, xr[j].z, b2);
                    b3 = fmaf(wx[j].w, xr[j].w, b3);
                }
                float s = (b0 + b1) + (b2 + b3);
                s += dpp_mov<0xB1>(s);
                if (phalf == 0) zxr[tp][pgq] = s + bb;
                tp += 4;
                if (tp < TT) {
                    const float* xp = xb + (size_t)tp * (BB * DD);
                    #pragma unroll
                    for (int j = 0; j < 16; ++j) xr[j] = *(const float4*)(xp + 4 * j);
                }
            }
        }

        bar_lds();   // barrier 1: pre[] visible

        // ---- phase B: E on waves 0-1; everyone else idles to the barrier ----
        if (tid < 128) {
            float p_f = (wv == 0) ? pa : pre[tid];
            float p_i = (wv == 1) ? pb : pre[128 + tid];
            float p_g = pre[256 + tid];
            float p_o = pre[384 + tid];
            float fg = rcp_f(1.f + exp2_f(p_f));
            float ig = rcp_f(1.f + exp2_f(p_i));
            float gg = fmaf(-2.f, rcp_f(1.f + exp2_f(p_g)), 1.f);
            float og = rcp_f(1.f + exp2_f(p_o));
            cst = fmaf(fg, cst, ig * gg);
            float tc = fmaf(-2.f, rcp_f(1.f + exp2_f(cst * 2.885390081777927f)), 1.f);
            float hn = og * tc;
            hn_last = hn;
            hbuf[tid + 4 * (tid >> 5)] = hn;
            p.out[orow] = hn;                    // issue-only
            orow += ostep;
        }
        bar_lds();   // barrier 2: hbuf ready for next step
    }

    // ---- tail: hx, cx ----
    if (tid < 128) {
        p.out[(size_t)TT * BB * HH + (size_t)bId * HH + tid] = hn_last;
        p.out[(size_t)TT * BB * HH + (size_t)BB * HH + (size_t)bId * HH + tid] = cst;
    }
}

extern "C" void kernel_launch(void* const* d_in, const int* in_sizes, int n_in,
                              void* d_out, int out_size, void* d_ws, size_t ws_size,
                              hipStream_t stream) {
    (void)in_sizes; (void)n_in; (void)out_size; (void)d_ws; (void)ws_size;
    Params p;
    p.x = (const float*)d_in[0];
    for (int g = 0; g < 4; ++g) {
        p.W[g]  = (const float*)d_in[1 + 5 * g + 0];
        p.b[g]  = (const float*)d_in[1 + 5 * g + 1];
        p.th[g] = (const float*)d_in[1 + 5 * g + 2];
        p.U[g]  = (const float*)d_in[1 + 5 * g + 3];
        p.cb[g] = (const float*)d_in[1 + 5 * g + 4];
    }
    p.out = (float*)d_out;
    hipLaunchKernelGGL(qlstm, dim3(BB), dim3(512), 0, stream, p);
}